// Round 8
// baseline (216.103 us; speedup 1.0000x reference)
//
#include <hip/hip_runtime.h>

#define L_SEQ 2048
#define NB    2
#define DMOD  1024
#define DIN   2048
#define NST   16
#define NROWS (NB*L_SEQ)   // 4096
#define CL    64
#define NC    (L_SEQ/CL)   // 32
#define LDA1  1056         // padded row stride (u16) for x16 / Bt1  (2112 B)
#define LDY   2112         // padded row stride (u16) for y16 / Bt3  (4224 B)

typedef unsigned short u16;
typedef _Float16 half8 __attribute__((ext_vector_type(8)));
typedef float f32x4 __attribute__((ext_vector_type(4)));
typedef short short8 __attribute__((ext_vector_type(8)));

__device__ __forceinline__ float siluf(float v){ return v / (1.f + __expf(-v)); }
__device__ __forceinline__ u16 f2h_bits(float v){ _Float16 h = (_Float16)v; return __builtin_bit_cast(u16, h); }
__device__ __forceinline__ float h2f(u16 v){ return (float)__builtin_bit_cast(_Float16, v); }
__device__ __forceinline__ float fexp2(float x){
#if __has_builtin(__builtin_amdgcn_exp2f)
    return __builtin_amdgcn_exp2f(x);
#else
    return __expf(x * 0.69314718056f);
#endif
}

// async global->LDS, 16B per lane; lds base wave-uniform; dest = base + lane*16
__device__ __forceinline__ void gload16(const u16* g, u16* l)
{
    __builtin_amdgcn_global_load_lds(
        (const __attribute__((address_space(1))) void*)g,
        (__attribute__((address_space(3))) void*)l,
        16, 0, 0);
}

// ---------------- fused input preprocessing ----------------
// blocks [0,4096): x f32 row -> x16 row (stride LDA1)
// blocks [4096,5120): W_in (1024x4096) -> Bt1 [4096][LDA1] f16
// blocks [5120,5632): W_out (2048x1024) -> Bt3 [1024][LDY] f16
// blocks [5632,6016): W_x (2048x33) -> WxT16 [48][2048] f16 zero-padded
__global__ __launch_bounds__(256)
void prep_inputs(const float* __restrict__ x, const float* __restrict__ W_in,
                 const float* __restrict__ W_out, const float* __restrict__ Wx,
                 u16* __restrict__ x16, u16* __restrict__ Bt1,
                 u16* __restrict__ Bt3, u16* __restrict__ WxT16)
{
    __shared__ float s[64][65];
    const int bid = blockIdx.x, tid = threadIdx.x;
    if (bid < 4096) {
        float4 v = ((const float4*)(x + (size_t)bid * DMOD))[tid];
        ushort4 o;
        o.x = f2h_bits(v.x); o.y = f2h_bits(v.y); o.z = f2h_bits(v.z); o.w = f2h_bits(v.w);
        *(ushort4*)&x16[(size_t)bid * LDA1 + tid * 4] = o;
    } else if (bid < 5632) {
        const float* in; u16* outT; int C, ldo, rblk, cblk;
        if (bid < 5120) { int b = bid - 4096; in = W_in;  outT = Bt1; C = 4096; ldo = LDA1; cblk = b & 63; rblk = b >> 6; }
        else            { int b = bid - 5120; in = W_out; outT = Bt3; C = 1024; ldo = LDY;  cblk = b & 15; rblk = b >> 4; }
        int r0 = rblk * 64, c0 = cblk * 64;
        int tc = tid & 63, ty = tid >> 6;
        #pragma unroll
        for (int j = 0; j < 16; j++) {
            int r = ty + j * 4;
            s[r][tc] = in[(size_t)(r0 + r) * C + c0 + tc];
        }
        __syncthreads();
        #pragma unroll
        for (int j = 0; j < 16; j++) {
            int nn = ty + j * 4;
            outT[(size_t)(c0 + nn) * ldo + r0 + tc] = f2h_bits(s[tc][nn]);
        }
    } else {
        int idx = (bid - 5632) * 256 + tid;        // 48*2048
        int n = idx >> 11, k = idx & 2047;
        float v = (n < 33) ? Wx[k * 33 + n] : 0.f;
        WxT16[idx] = f2h_bits(v);
    }
}

// ---------------- MFMA GEMM: 128xBN tile, BK=64, gload_lds + src-swizzle, 2-phase dbuf ----
// XCD-chunked bijective blockIdx swizzle (nwg % 8 == 0 required).
// LDS holds T[row][slot] = G[row][slot ^ (row&7)] (16B units); K-tiles double-buffered.
// EPI==1: split at N/2: col<half -> C0h (u16) ; else C1h = silu (u16)
// EPI==2: u16 partial at C0h[(z*M + row)*N + col]
template<int BN, int EPI, int GX>
__global__ __launch_bounds__(256)
void gemm_mfma(const u16* __restrict__ A, const u16* __restrict__ Bt,
               void* __restrict__ C0v, void* __restrict__ C1v,
               int M, int N, int KLEN, int lda, int ldb)
{
    constexpr int NI = BN / 32;                    // B-frags per wave
    __shared__ __align__(16) u16 As0[128 * 64], As1[128 * 64];
    __shared__ __align__(16) u16 Bs0[BN * 64],  Bs1[BN * 64];
    const int tid  = threadIdx.x;
    const int lane = tid & 63;
    const int wid  = tid >> 6;
    const int wm   = wid >> 1, wn = wid & 1;

    // XCD swizzle: consecutive HW ids round-robin XCDs; remap so each XCD gets a
    // contiguous chunk of logical (by-major) tile ids -> same-A-panel locality per XCD.
    const int nwg  = GX * gridDim.y;
    const int orig = blockIdx.y * GX + blockIdx.x;
    const int wg   = (orig & 7) * (nwg >> 3) + (orig >> 3);
    const int bm = (wg / GX) * 128, bn = (wg % GX) * BN;
    const int kBase = blockIdx.z * KLEN;

    // staging: call c covers rows c*8..c*8+7; lane l -> row c*8+(l>>3), slot (l&7)
    // source pre-swizzle: global unit = (l&7) ^ (l>>3)
    const int srow8 = lane >> 3;
    const int sunit = (lane & 7) ^ srow8;
    const u16* Ag = A  + (size_t)(bm + srow8) * lda + kBase + sunit * 8;
    const u16* Bg = Bt + (size_t)(bn + srow8) * ldb + kBase + sunit * 8;

    // fragment read offsets (elements), hoisted; kk=1 = kk=0 ^ 32 (slot-bit XOR only)
    const int fr = lane & 15;
    const int s0 = (((lane >> 4) ^ (lane & 7))) * 8;
    const int aBase = (wm * 64 + fr) * 64 + s0;
    const int bBase = (wn * (BN / 2) + fr) * 64 + s0;

    f32x4 acc[4][NI];
    #pragma unroll
    for (int i = 0; i < 4; i++)
        #pragma unroll
        for (int j = 0; j < NI; j++)
            acc[i][j] = (f32x4){0.f, 0.f, 0.f, 0.f};

    auto STAGE = [&](u16* Ab, u16* Bb, int k0) {
        #pragma unroll
        for (int j = 0; j < 4; j++) {              // A: 16 calls (4/wave)
            int c = wid * 4 + j;
            gload16(Ag + (size_t)(c * 8) * lda + k0, Ab + c * 512);
        }
        #pragma unroll
        for (int j = 0; j < NI; j++) {             // B: BN/8 calls (NI/wave)
            int c = wid * NI + j;
            gload16(Bg + (size_t)(c * 8) * ldb + k0, Bb + c * 512);
        }
    };

    auto COMPUTE = [&](const u16* Ab, const u16* Bb) {
        #pragma unroll
        for (int kk = 0; kk < 2; kk++) {
            const int x = kk ? 32 : 0;
            half8 af[4], bf[NI];
            #pragma unroll
            for (int mi = 0; mi < 4; mi++)
                af[mi] = *(const half8*)&Ab[(aBase ^ x) + mi * 1024];
            #pragma unroll
            for (int ni = 0; ni < NI; ni++)
                bf[ni] = *(const half8*)&Bb[(bBase ^ x) + ni * 1024];
            #pragma unroll
            for (int mi = 0; mi < 4; mi++)
                #pragma unroll
                for (int ni = 0; ni < NI; ni++)
                    acc[mi][ni] = __builtin_amdgcn_mfma_f32_16x16x32_f16(af[mi], bf[ni], acc[mi][ni], 0, 0, 0);
        }
    };

    const int NT = KLEN >> 6;                       // even for all our shapes
    STAGE(As0, Bs0, 0);
    __syncthreads();                                // drain vmcnt: tile 0 ready
    for (int t = 0; t < NT; t += 2) {
        if (t + 1 < NT) STAGE(As1, Bs1, (t + 1) << 6);
        COMPUTE(As0, Bs0);
        __syncthreads();                            // tile t+1 ready; As0 free
        if (t + 2 < NT) STAGE(As0, Bs0, (t + 2) << 6);
        if (t + 1 < NT) COMPUTE(As1, Bs1);
        __syncthreads();                            // tile t+2 ready; As1 free
    }

    const int cr = (lane >> 4) * 4;
    const int cc = lane & 15;
    #pragma unroll
    for (int mi = 0; mi < 4; mi++) {
        #pragma unroll
        for (int ni = 0; ni < NI; ni++) {
            #pragma unroll
            for (int q = 0; q < 4; q++) {
                int row = bm + wm * 64 + mi * 16 + cr + q;
                int col = bn + wn * (BN / 2) + ni * 16 + cc;
                float v = acc[mi][ni][q];
                if (EPI == 1) {
                    int half = N >> 1;
                    if (col < half) ((u16*)C0v)[(size_t)row * half + col] = f2h_bits(v);
                    else            ((u16*)C1v)[(size_t)row * half + col - half] = f2h_bits(siluf(v));
                } else {
                    ((u16*)C0v)[((size_t)blockIdx.z * M + row) * N + col] = f2h_bits(v);
                }
            }
        }
    }
}

// ---------------- sum the two split-K f16 partials -> fp32 out ----------------
__global__ __launch_bounds__(256)
void add_partials(const u16* __restrict__ p, float* __restrict__ out)
{
    int i = blockIdx.x * 256 + threadIdx.x;        // over 4096*1024/8
    short8 a = *(const short8*)&p[(size_t)i * 8];
    short8 b = *(const short8*)&p[(size_t)NROWS * DMOD + (size_t)i * 8];
    float4 o0, o1;
    o0.x = h2f((u16)a[0]) + h2f((u16)b[0]);
    o0.y = h2f((u16)a[1]) + h2f((u16)b[1]);
    o0.z = h2f((u16)a[2]) + h2f((u16)b[2]);
    o0.w = h2f((u16)a[3]) + h2f((u16)b[3]);
    o1.x = h2f((u16)a[4]) + h2f((u16)b[4]);
    o1.y = h2f((u16)a[5]) + h2f((u16)b[5]);
    o1.z = h2f((u16)a[6]) + h2f((u16)b[6]);
    o1.w = h2f((u16)a[7]) + h2f((u16)b[7]);
    *(float4*)&out[(size_t)i * 8]     = o0;
    *(float4*)&out[(size_t)i * 8 + 4] = o1;
}

// ---------------- depthwise causal conv (4 taps) + bias + SiLU, fp16 io ----------------
__global__ __launch_bounds__(256)
void conv_silu16(const u16* __restrict__ xin16, const float* __restrict__ cw,
                 const float* __restrict__ cb, u16* __restrict__ xc16)
{
    int idx = blockIdx.x * 256 + threadIdx.x;      // (b,t,d8): NB*L*DIN/8
    int d8 = idx & 255;
    int t  = (idx >> 8) & (L_SEQ - 1);
    int b  = idx >> 19;
    int d  = d8 << 3;
    const float4* cw4 = (const float4*)cw;
    float4 w[8];
    #pragma unroll
    for (int j = 0; j < 8; j++) w[j] = cw4[d + j];
    float acc[8];
    {
        float4 b0 = *(const float4*)&cb[d];
        float4 b1 = *(const float4*)&cb[d + 4];
        acc[0]=b0.x; acc[1]=b0.y; acc[2]=b0.z; acc[3]=b0.w;
        acc[4]=b1.x; acc[5]=b1.y; acc[6]=b1.z; acc[7]=b1.w;
    }
    #pragma unroll
    for (int k = 0; k < 4; k++) {
        int tt = t + k - 3;
        if (tt >= 0) {
            short8 v = *(const short8*)&xin16[((size_t)(b * L_SEQ + tt)) * DIN + d];
            #pragma unroll
            for (int j = 0; j < 8; j++)
                acc[j] = fmaf(h2f((u16)v[j]), (&w[j].x)[k], acc[j]);
        }
    }
    short8 o;
    #pragma unroll
    for (int j = 0; j < 8; j++) o[j] = (short)f2h_bits(siluf(acc[j]));
    *(short8*)&xc16[(size_t)idx * 8] = o;
}

// ---------------- GEMM2: [4096][2048] @ [48][2048]^T, K-split 8, tile M=64 ----------------
__global__ __launch_bounds__(256)
void gemm2_mfma(const u16* __restrict__ A, const u16* __restrict__ Bt, float* __restrict__ pb)
{
    __shared__ __align__(16) u16 As[64 * 64];
    __shared__ __align__(16) u16 Bs[48 * 64];
    const int tid = threadIdx.x, lane = tid & 63, w = tid >> 6;
    const int bm = blockIdx.x * 64;
    const int kz = blockIdx.y;
    const int arow = tid >> 2;          // 0..63
    const int au   = (tid & 3) << 1;    // unit pair
    f32x4 acc[3];
    acc[0] = acc[1] = acc[2] = (f32x4){0.f, 0.f, 0.f, 0.f};

    for (int it = 0; it < 4; ++it) {
        const int k0 = kz * 256 + it * 64;
        short8 ra0 = *(const short8*)&A[(size_t)(bm + arow) * DIN + k0 + au * 8];
        short8 ra1 = *(const short8*)&A[(size_t)(bm + arow) * DIN + k0 + (au + 1) * 8];
        short8 rb0, rb1;
        if (tid < 192) {
            rb0 = *(const short8*)&Bt[(size_t)arow * DIN + k0 + au * 8];
            rb1 = *(const short8*)&Bt[(size_t)arow * DIN + k0 + (au + 1) * 8];
        }
        __syncthreads();
        {
            int s0 = au ^ (arow & 7), s1 = (au + 1) ^ (arow & 7);
            *(short8*)&As[arow * 64 + s0 * 8] = ra0;
            *(short8*)&As[arow * 64 + s1 * 8] = ra1;
            if (tid < 192) {
                *(short8*)&Bs[arow * 64 + s0 * 8] = rb0;
                *(short8*)&Bs[arow * 64 + s1 * 8] = rb1;
            }
        }
        __syncthreads();
        #pragma unroll
        for (int kk = 0; kk < 2; kk++) {
            int r = w * 16 + (lane & 15);
            int sl = (kk * 4 + (lane >> 4)) ^ (r & 7);
            half8 af = *(const half8*)&As[r * 64 + sl * 8];
            #pragma unroll
            for (int ni = 0; ni < 3; ni++) {
                int br = ni * 16 + (lane & 15);
                int bsl = (kk * 4 + (lane >> 4)) ^ (br & 7);
                half8 bf = *(const half8*)&Bs[br * 64 + bsl * 8];
                acc[ni] = __builtin_amdgcn_mfma_f32_16x16x32_f16(af, bf, acc[ni], 0, 0, 0);
            }
        }
    }
    #pragma unroll
    for (int ni = 0; ni < 3; ni++) {
        #pragma unroll
        for (int q = 0; q < 4; q++) {
            int row = bm + w * 16 + (lane >> 4) * 4 + q;
            int col = ni * 16 + (lane & 15);
            pb[((size_t)kz * NROWS + row) * 48 + col] = acc[ni][q];
        }
    }
}

// ---------------- GEMM2 reduce: sum 8 partials, softplus col0, split B/C ----------------
__global__ __launch_bounds__(256)
void gemm2_reduce(const float* __restrict__ pb, float* __restrict__ delta,
                  float* __restrict__ Bm, float* __restrict__ Cm)
{
    int idx = blockIdx.x * 256 + threadIdx.x;      // 4096*48
    int row = idx / 48, col = idx - row * 48;
    float s = 0.f;
    #pragma unroll
    for (int kz = 0; kz < 8; kz++) s += pb[(size_t)kz * NROWS * 48 + idx];
    if (col == 0)       delta[row] = fmaxf(s, 0.f) + log1pf(__expf(-fabsf(s)));
    else if (col < 17)  Bm[row * NST + col - 1]  = s;
    else if (col < 33)  Cm[row * NST + col - 17] = s;
}

// ---------------- scan pass 1: thread-per-d, h[16] in regs ----------------
__global__ __launch_bounds__(256)
void scan_part1_reg(const u16* __restrict__ xc16, const float* __restrict__ delta,
                    const float* __restrict__ Bm, const float* __restrict__ A_log,
                    float* __restrict__ h_loc, float* __restrict__ Pc)
{
    const int b = blockIdx.z, c = blockIdx.y;
    const int d = blockIdx.x * 256 + threadIdx.x;
    float ka[16];
    {
        const float4* Av = (const float4*)(A_log + (size_t)d * 16);
        #pragma unroll
        for (int q = 0; q < 4; q++) {
            float4 a = Av[q];
            ka[q*4+0] = -__expf(a.x) * 1.44269504f;
            ka[q*4+1] = -__expf(a.y) * 1.44269504f;
            ka[q*4+2] = -__expf(a.z) * 1.44269504f;
            ka[q*4+3] = -__expf(a.w) * 1.44269504f;
        }
    }
    float h[16];
    #pragma unroll
    for (int n = 0; n < 16; n++) h[n] = 0.f;
    float S = 0.f;
    const int rowbase = b * L_SEQ + c * CL;
    #pragma unroll 2
    for (int t = 0; t < CL; ++t) {
        const int rowg = rowbase + t;
        const float dt = delta[rowg];
        const float4* Bv = (const float4*)(Bm + (size_t)rowg * 16);
        float4 b0 = Bv[0], b1 = Bv[1], b2 = Bv[2], b3 = Bv[3];
        float bb[16] = {b0.x,b0.y,b0.z,b0.w, b1.x,b1.y,b1.z,b1.w,
                        b2.x,b2.y,b2.z,b2.w, b3.x,b3.y,b3.z,b3.w};
        const float xt = h2f(xc16[(size_t)rowg * DIN + d]);
        const float dtx = dt * xt;
        S += dt;
        #pragma unroll
        for (int n = 0; n < 16; n++) {
            float a = fexp2(dt * ka[n]);
            h[n] = fmaf(a, h[n], bb[n] * dtx);
        }
    }
    float* hp = h_loc + (((size_t)(b * NC + c) * DIN) + d) * 16;
    float* pp = Pc    + (((size_t)(b * NC + c) * DIN) + d) * 16;
    #pragma unroll
    for (int q = 0; q < 4; q++) {
        *(float4*)&hp[q*4] = (float4){h[q*4+0], h[q*4+1], h[q*4+2], h[q*4+3]};
        *(float4*)&pp[q*4] = (float4){fexp2(S*ka[q*4+0]), fexp2(S*ka[q*4+1]),
                                      fexp2(S*ka[q*4+2]), fexp2(S*ka[q*4+3])};
    }
}

// ---------------- scan pass 2: sequential carry across chunks ----------------
__global__ __launch_bounds__(256)
void scan_carry(const float* __restrict__ h_loc, const float* __restrict__ Pc,
                float* __restrict__ H_in)
{
    int gid = blockIdx.x * 256 + threadIdx.x;      // NB*DIN*NST = 65536
    int b = gid >> 15, r = gid & 32767;
    float H = 0.f;
    for (int c = 0; c < NC; ++c) {
        size_t idx = ((size_t)(b * NC + c) << 15) + r;
        H_in[idx] = H;
        H = fmaf(Pc[idx], H, h_loc[idx]);
    }
}

// ---------------- scan pass 3: thread-per-d, fused epilogue -> y fp16 (stride LDY) ----
__global__ __launch_bounds__(256)
void scan_part3_reg(const u16* __restrict__ xc16, const float* __restrict__ delta,
                    const float* __restrict__ Bm, const float* __restrict__ Cm,
                    const float* __restrict__ A_log, const float* __restrict__ Dp,
                    const u16* __restrict__ res16, const float* __restrict__ H_in,
                    u16* __restrict__ yh)
{
    const int b = blockIdx.z, c = blockIdx.y;
    const int d = blockIdx.x * 256 + threadIdx.x;
    float ka[16];
    {
        const float4* Av = (const float4*)(A_log + (size_t)d * 16);
        #pragma unroll
        for (int q = 0; q < 4; q++) {
            float4 a = Av[q];
            ka[q*4+0] = -__expf(a.x) * 1.44269504f;
            ka[q*4+1] = -__expf(a.y) * 1.44269504f;
            ka[q*4+2] = -__expf(a.z) * 1.44269504f;
            ka[q*4+3] = -__expf(a.w) * 1.44269504f;
        }
    }
    float h[16];
    {
        const float4* Hv = (const float4*)(H_in + (((size_t)(b * NC + c) * DIN) + d) * 16);
        #pragma unroll
        for (int q = 0; q < 4; q++) {
            float4 v = Hv[q];
            h[q*4+0]=v.x; h[q*4+1]=v.y; h[q*4+2]=v.z; h[q*4+3]=v.w;
        }
    }
    const float Dpd = Dp[d];
    const int rowbase = b * L_SEQ + c * CL;
    #pragma unroll 2
    for (int t = 0; t < CL; ++t) {
        const int rowg = rowbase + t;
        const float dt = delta[rowg];
        const float4* Bv = (const float4*)(Bm + (size_t)rowg * 16);
        const float4* Cv = (const float4*)(Cm + (size_t)rowg * 16);
        float4 b0 = Bv[0], b1 = Bv[1], b2 = Bv[2], b3 = Bv[3];
        float4 c0 = Cv[0], c1 = Cv[1], c2 = Cv[2], c3 = Cv[3];
        float bb[16] = {b0.x,b0.y,b0.z,b0.w, b1.x,b1.y,b1.z,b1.w,
                        b2.x,b2.y,b2.z,b2.w, b3.x,b3.y,b3.z,b3.w};
        float cc[16] = {c0.x,c0.y,c0.z,c0.w, c1.x,c1.y,c1.z,c1.w,
                        c2.x,c2.y,c2.z,c2.w, c3.x,c3.y,c3.z,c3.w};
        const float xt = h2f(xc16[(size_t)rowg * DIN + d]);
        const float rt = h2f(res16[(size_t)rowg * DIN + d]);
        const float dtx = dt * xt;
        float y = 0.f;
        #pragma unroll
        for (int n = 0; n < 16; n++) {
            float a = fexp2(dt * ka[n]);
            h[n] = fmaf(a, h[n], bb[n] * dtx);
            y = fmaf(cc[n], h[n], y);
        }
        y = (y + xt * Dpd) * rt;
        yh[(size_t)rowg * LDY + d] = f2h_bits(y);
    }
}

extern "C" void kernel_launch(void* const* d_in, const int* in_sizes, int n_in,
                              void* d_out, int out_size, void* d_ws, size_t ws_size,
                              hipStream_t stream)
{
    const float* x     = (const float*)d_in[0];
    const float* W_in  = (const float*)d_in[1];
    const float* cw    = (const float*)d_in[2];
    const float* cb    = (const float*)d_in[3];
    const float* Wx    = (const float*)d_in[4];
    const float* A_log = (const float*)d_in[5];
    const float* Dp    = (const float*)d_in[6];
    const float* W_out = (const float*)d_in[7];
    float* out = (float*)d_out;
    float* ws  = (float*)d_ws;

    // workspace layout (float slot offsets); aliases valid by stream-order lifetimes:
    u16*   xin16 = (u16*)(ws);                     // [4096][2048] ; dead after conv
    u16*   y16   = (u16*)(ws);                     // [4096][LDY] (over xin16, 4,325,376 fl)
    u16*   res16 = (u16*)(ws + 4325376);           // [4096][2048]
    u16*   xc16  = (u16*)(ws + 8519680);           // [4096][2048]
    u16*   x16   = (u16*)(ws + 12713984);          // [4096][LDA1] ; dead after GEMM1
    float* pb    = ws + 12713984;                  // [8][4096][48] f32 (alias x16)
    u16*   Bt1   = (u16*)(ws + 14876672);          // [4096][LDA1] ; dead after GEMM1
    u16*   p     = (u16*)(ws + 14876672);          // [2][4096][1024] (alias Bt1..Cm, all dead at GEMM3)
    u16*   WxT16 = (u16*)(ws + 17039360);          // [48][2048]
    float* delta = ws + 17088512;                  // 4096
    float* Bm    = ws + 17092608;                  // 65536
    float* Cm    = ws + 17158144;                  // 65536
    float* h_loc = ws + 17223680;                  // 2097152
    float* Pc    = ws + 19320832;                  // 2097152
    float* H_in  = ws + 21417984;                  // 2097152
    u16*   Bt3   = (u16*)(ws + 23515136);          // [1024][LDY] (end 24,596,480 fl = 98.4 MB)

    dim3 blk(256);

    // 1) fused preprocessing: x->f16 (LDA1), W_in^T (LDA1), W_out^T (LDY), W_x^T
    prep_inputs<<<dim3(6016), blk, 0, stream>>>(x, W_in, W_out, Wx, x16, Bt1, Bt3, WxT16);
    // 2) GEMM1 -> xin16 | silu(res)16
    gemm_mfma<128, 1, 32><<<dim3(32, 32), blk, 0, stream>>>(x16, Bt1, xin16, res16,
                                                            NROWS, 2 * DIN, DMOD, LDA1, LDA1);
    // 3) conv + bias + silu (fp16 io)
    conv_silu16<<<dim3(NB * L_SEQ * (DIN / 8) / 256), blk, 0, stream>>>(xin16, cw, cb, xc16);
    // 4) ssm params: MFMA K-split GEMM, reduce+softplus
    gemm2_mfma<<<dim3(NROWS / 64, 8), blk, 0, stream>>>(xc16, WxT16, pb);
    gemm2_reduce<<<dim3(NROWS * 48 / 256), blk, 0, stream>>>(pb, delta, Bm, Cm);
    // 5) chunk-parallel scan (thread-per-d, regs), CL=64
    scan_part1_reg<<<dim3(DIN / 256, NC, NB), blk, 0, stream>>>(xc16, delta, Bm, A_log, h_loc, Pc);
    scan_carry<<<dim3(NB * DIN * NST / 256), blk, 0, stream>>>(h_loc, Pc, H_in);
    scan_part3_reg<<<dim3(DIN / 256, NC, NB), blk, 0, stream>>>(xc16, delta, Bm, Cm, A_log, Dp, res16, H_in, y16);
    // 6) GEMM3 split-K=2: p[z] = y[:, z*1024:(z+1)*1024] @ W_out[z*1024:(z+1)*1024, :]
    gemm_mfma<128, 2, 8><<<dim3(DMOD / 128, NROWS / 128, 2), blk, 0, stream>>>(y16, Bt3, p, nullptr,
                                                                               NROWS, DMOD, DIN / 2, LDY, LDY);
    // 7) out = p[0] + p[1] (fp32)
    add_partials<<<dim3(NROWS * DMOD / 8 / 256), blk, 0, stream>>>(p, out);
}

// Round 9
// 207.328 us; speedup vs baseline: 1.0423x; 1.0423x over previous
//
#include <hip/hip_runtime.h>

#define L_SEQ 2048
#define NB    2
#define DMOD  1024
#define DIN   2048
#define NST   16
#define NROWS (NB*L_SEQ)   // 4096
#define CL    64
#define NC    (L_SEQ/CL)   // 32

typedef unsigned short u16;
typedef _Float16 half8 __attribute__((ext_vector_type(8)));
typedef float f32x4 __attribute__((ext_vector_type(4)));
typedef short short8 __attribute__((ext_vector_type(8)));

__device__ __forceinline__ float siluf(float v){ return v / (1.f + __expf(-v)); }
__device__ __forceinline__ u16 f2h_bits(float v){ _Float16 h = (_Float16)v; return __builtin_bit_cast(u16, h); }
__device__ __forceinline__ float h2f(u16 v){ return (float)__builtin_bit_cast(_Float16, v); }
__device__ __forceinline__ float fexp2(float x){
#if __has_builtin(__builtin_amdgcn_exp2f)
    return __builtin_amdgcn_exp2f(x);
#else
    return __expf(x * 0.69314718056f);
#endif
}

// async global->LDS, 16B per lane; lds base wave-uniform; dest = base + lane*16
__device__ __forceinline__ void gload16(const u16* g, u16* l)
{
    __builtin_amdgcn_global_load_lds(
        (const __attribute__((address_space(1))) void*)g,
        (__attribute__((address_space(3))) void*)l,
        16, 0, 0);
}

#define BARRIER() do { asm volatile("" ::: "memory"); __builtin_amdgcn_s_barrier(); asm volatile("" ::: "memory"); } while (0)
#define VMCNT2()  asm volatile("s_waitcnt vmcnt(2)" ::: "memory")

// ---------------- fused input preprocessing ----------------
// blocks [0,4096): x f32 -> x16 ; [4096,5120): W_in^T f16 ; [5120,5632): W_out^T f16 ;
// [5632,6016): W_x -> WxT16 [48][2048] zero-padded
__global__ __launch_bounds__(256)
void prep_inputs(const float* __restrict__ x, const float* __restrict__ W_in,
                 const float* __restrict__ W_out, const float* __restrict__ Wx,
                 u16* __restrict__ x16, u16* __restrict__ Bt1,
                 u16* __restrict__ Bt3, u16* __restrict__ WxT16)
{
    __shared__ float s[64][65];
    const int bid = blockIdx.x, tid = threadIdx.x;
    if (bid < 4096) {
        int i = bid * 256 + tid;                   // over NROWS*DMOD/4
        float4 v = ((const float4*)x)[i];
        ushort4 o;
        o.x = f2h_bits(v.x); o.y = f2h_bits(v.y); o.z = f2h_bits(v.z); o.w = f2h_bits(v.w);
        *(ushort4*)&x16[(size_t)i * 4] = o;
    } else if (bid < 5632) {
        const float* in; u16* outT; int R, C, rblk, cblk;
        if (bid < 5120) { int b = bid - 4096; in = W_in;  outT = Bt1; R = 1024; C = 4096; cblk = b & 63; rblk = b >> 6; }
        else            { int b = bid - 5120; in = W_out; outT = Bt3; R = 2048; C = 1024; cblk = b & 15; rblk = b >> 4; }
        int r0 = rblk * 64, c0 = cblk * 64;
        int tc = tid & 63, ty = tid >> 6;
        #pragma unroll
        for (int j = 0; j < 16; j++) {
            int r = ty + j * 4;
            s[r][tc] = in[(size_t)(r0 + r) * C + c0 + tc];
        }
        __syncthreads();
        #pragma unroll
        for (int j = 0; j < 16; j++) {
            int nn = ty + j * 4;
            outT[(size_t)(c0 + nn) * R + r0 + tc] = f2h_bits(s[tc][nn]);
        }
    } else {
        int idx = (bid - 5632) * 256 + tid;        // 48*2048
        int n = idx >> 11, k = idx & 2047;
        float v = (n < 33) ? Wx[k * 33 + n] : 0.f;
        WxT16[idx] = f2h_bits(v);
    }
}

// ---------------- 8-phase-style MFMA GEMM: 256x256 tile, BK=64, 8 waves, 512 thr ----------
// Raw s_barrier + counted vmcnt(2); never drains to 0 in the loop.
// Stage order per tile t+1: ph0 A-h0, ph1 A-h1, ph2 B-h0, ph3 B-h1 (into buf (t+1)&1).
// Compute partition: ph0 (kk0, ni01), ph1 (kk0, ni23), ph2 (kk1, ni01), ph3 (kk1, ni23).
// Dep check: ph0(t) reads A(t)+B-h0(t) [staged ph0-2 of t-1] -> vmcnt(2) at ph3(t-1) end
//            ph1(t) reads B-h1(t) [staged ph3(t-1)]          -> vmcnt(2) at ph0(t) end
// EPI==1: split N at half: col<half -> C0h (u16) ; else C1h = silu (u16)
// EPI==2: u16 partial at C0h[(z*M + row)*N + col]
template<int EPI>
__global__ __launch_bounds__(512, 2)
void gemm8(const u16* __restrict__ A, const u16* __restrict__ Bt,
           void* __restrict__ C0v, void* __restrict__ C1v,
           int M, int N, int KLEN, int lda, int ldb)
{
    __shared__ __align__(16) u16 As[2 * 256 * 64];   // 64 KB (2 bufs)
    __shared__ __align__(16) u16 Bs[2 * 256 * 64];   // 64 KB
    const int tid  = threadIdx.x;
    const int lane = tid & 63;
    const int w    = tid >> 6;                 // 0..7
    const int wm   = w >> 2, wn = w & 3;       // 2 x 4 wave grid
    const int bm = blockIdx.y * 256, bn = blockIdx.x * 256;
    const int kBase = blockIdx.z * KLEN;

    // staging: lane l -> row +(l>>3), 16B unit (l&7); source pre-swizzled unit
    const int srow8 = lane >> 3;
    const int sunit = (lane & 7) ^ srow8;
    const u16* Ag = A  + (size_t)(bm + srow8) * lda + kBase + sunit * 8;
    const u16* Bg = Bt + (size_t)(bn + srow8) * ldb + kBase + sunit * 8;
    const int rw = w * 16;                     // wave's stage-row base within a half

    // fragment offsets (elements within one buf); kk=1 -> ^32
    const int fr  = lane & 15;
    const int sl0 = ((lane >> 4) ^ (fr & 7)) * 8;
    int aOffs[8], bOffs[4];
    #pragma unroll
    for (int mi = 0; mi < 8; mi++) aOffs[mi] = (wm * 128 + mi * 16 + fr) * 64 + sl0;
    #pragma unroll
    for (int ni = 0; ni < 4; ni++) bOffs[ni] = (ni * 64 + wn * 16 + fr) * 64 + sl0;

    f32x4 acc[8][4];
    #pragma unroll
    for (int i = 0; i < 8; i++)
        #pragma unroll
        for (int j = 0; j < 4; j++)
            acc[i][j] = (f32x4){0.f, 0.f, 0.f, 0.f};

    // stage one half-tile (2 gloads): rows h*128+rw..+15 of next-buf operand
    auto stage2 = [&](const u16* G, int ld, int rbase, int kcol, u16* ldsDst) {
        gload16(G + (size_t)rbase * ld + kcol, ldsDst);
        gload16(G + (size_t)(rbase + 8) * ld + kcol, ldsDst + 8 * 64);
    };

    const int NT = KLEN >> 6;
    // prologue: stage tile 0 fully into buf 0
    stage2(Ag, lda, 0 + rw, 0, &As[(0 + rw) * 64]);
    stage2(Ag, lda, 128 + rw, 0, &As[(128 + rw) * 64]);
    stage2(Bg, ldb, 0 + rw, 0, &Bs[(0 + rw) * 64]);
    stage2(Bg, ldb, 128 + rw, 0, &Bs[(128 + rw) * 64]);
    VMCNT2();
    BARRIER();

    for (int t = 0; t < NT; ++t) {
        const int cO = (t & 1) << 14;          // current buf elem offset
        const int nO = cO ^ 16384;             // next buf
        const int kn = (t + 1) << 6;
        const bool pf = (t + 1) < NT;
        half8 af[8], bf0, bf1;

        // ---- phase 0: A kk0 (8 reads) + B kk0 ni{0,1}; stage A-h0(t+1)
        #pragma unroll
        for (int mi = 0; mi < 8; mi++) af[mi] = *(const half8*)&As[cO + aOffs[mi]];
        bf0 = *(const half8*)&Bs[cO + bOffs[0]];
        bf1 = *(const half8*)&Bs[cO + bOffs[1]];
        if (pf) stage2(Ag, lda, 0 + rw, kn, &As[nO + (0 + rw) * 64]);
        BARRIER();
        __builtin_amdgcn_s_setprio(1);
        #pragma unroll
        for (int mi = 0; mi < 8; mi++) acc[mi][0] = __builtin_amdgcn_mfma_f32_16x16x32_f16(af[mi], bf0, acc[mi][0], 0, 0, 0);
        #pragma unroll
        for (int mi = 0; mi < 8; mi++) acc[mi][1] = __builtin_amdgcn_mfma_f32_16x16x32_f16(af[mi], bf1, acc[mi][1], 0, 0, 0);
        __builtin_amdgcn_s_setprio(0);
        VMCNT2();
        BARRIER();

        // ---- phase 1: B kk0 ni{2,3}; stage A-h1(t+1)
        bf0 = *(const half8*)&Bs[cO + bOffs[2]];
        bf1 = *(const half8*)&Bs[cO + bOffs[3]];
        if (pf) stage2(Ag, lda, 128 + rw, kn, &As[nO + (128 + rw) * 64]);
        BARRIER();
        __builtin_amdgcn_s_setprio(1);
        #pragma unroll
        for (int mi = 0; mi < 8; mi++) acc[mi][2] = __builtin_amdgcn_mfma_f32_16x16x32_f16(af[mi], bf0, acc[mi][2], 0, 0, 0);
        #pragma unroll
        for (int mi = 0; mi < 8; mi++) acc[mi][3] = __builtin_amdgcn_mfma_f32_16x16x32_f16(af[mi], bf1, acc[mi][3], 0, 0, 0);
        __builtin_amdgcn_s_setprio(0);
        BARRIER();

        // ---- phase 2: A kk1 (8 reads) + B kk1 ni{0,1}; stage B-h0(t+1)
        #pragma unroll
        for (int mi = 0; mi < 8; mi++) af[mi] = *(const half8*)&As[cO + (aOffs[mi] ^ 32)];
        bf0 = *(const half8*)&Bs[cO + (bOffs[0] ^ 32)];
        bf1 = *(const half8*)&Bs[cO + (bOffs[1] ^ 32)];
        if (pf) stage2(Bg, ldb, 0 + rw, kn, &Bs[nO + (0 + rw) * 64]);
        BARRIER();
        __builtin_amdgcn_s_setprio(1);
        #pragma unroll
        for (int mi = 0; mi < 8; mi++) acc[mi][0] = __builtin_amdgcn_mfma_f32_16x16x32_f16(af[mi], bf0, acc[mi][0], 0, 0, 0);
        #pragma unroll
        for (int mi = 0; mi < 8; mi++) acc[mi][1] = __builtin_amdgcn_mfma_f32_16x16x32_f16(af[mi], bf1, acc[mi][1], 0, 0, 0);
        __builtin_amdgcn_s_setprio(0);
        BARRIER();

        // ---- phase 3: B kk1 ni{2,3}; stage B-h1(t+1)
        bf0 = *(const half8*)&Bs[cO + (bOffs[2] ^ 32)];
        bf1 = *(const half8*)&Bs[cO + (bOffs[3] ^ 32)];
        if (pf) stage2(Bg, ldb, 128 + rw, kn, &Bs[nO + (128 + rw) * 64]);
        BARRIER();
        __builtin_amdgcn_s_setprio(1);
        #pragma unroll
        for (int mi = 0; mi < 8; mi++) acc[mi][2] = __builtin_amdgcn_mfma_f32_16x16x32_f16(af[mi], bf0, acc[mi][2], 0, 0, 0);
        #pragma unroll
        for (int mi = 0; mi < 8; mi++) acc[mi][3] = __builtin_amdgcn_mfma_f32_16x16x32_f16(af[mi], bf1, acc[mi][3], 0, 0, 0);
        __builtin_amdgcn_s_setprio(0);
        VMCNT2();
        BARRIER();
    }

    const int cr = (lane >> 4) * 4;
    #pragma unroll
    for (int mi = 0; mi < 8; mi++) {
        #pragma unroll
        for (int ni = 0; ni < 4; ni++) {
            #pragma unroll
            for (int q = 0; q < 4; q++) {
                int row = bm + wm * 128 + mi * 16 + cr + q;
                int col = bn + ni * 64 + wn * 16 + fr;
                float v = acc[mi][ni][q];
                if (EPI == 1) {
                    int half = N >> 1;
                    if (col < half) ((u16*)C0v)[(size_t)row * half + col] = f2h_bits(v);
                    else            ((u16*)C1v)[(size_t)row * half + col - half] = f2h_bits(siluf(v));
                } else {
                    ((u16*)C0v)[((size_t)blockIdx.z * M + row) * N + col] = f2h_bits(v);
                }
            }
        }
    }
}

// ---------------- sum the four split-K f16 partials -> fp32 out ----------------
__global__ __launch_bounds__(256)
void add_partials4(const u16* __restrict__ p, float* __restrict__ out)
{
    int i = blockIdx.x * 256 + threadIdx.x;        // over 4096*1024/8
    const size_t stride = (size_t)NROWS * DMOD;
    float acc[8] = {0,0,0,0,0,0,0,0};
    #pragma unroll
    for (int z = 0; z < 4; z++) {
        short8 a = *(const short8*)&p[z * stride + (size_t)i * 8];
        #pragma unroll
        for (int j = 0; j < 8; j++) acc[j] += h2f((u16)a[j]);
    }
    float4 o0 = {acc[0], acc[1], acc[2], acc[3]};
    float4 o1 = {acc[4], acc[5], acc[6], acc[7]};
    *(float4*)&out[(size_t)i * 8]     = o0;
    *(float4*)&out[(size_t)i * 8 + 4] = o1;
}

// ---------------- depthwise causal conv (4 taps) + bias + SiLU, fp16 io ----------------
__global__ __launch_bounds__(256)
void conv_silu16(const u16* __restrict__ xin16, const float* __restrict__ cw,
                 const float* __restrict__ cb, u16* __restrict__ xc16)
{
    int idx = blockIdx.x * 256 + threadIdx.x;      // (b,t,d8): NB*L*DIN/8
    int d8 = idx & 255;
    int t  = (idx >> 8) & (L_SEQ - 1);
    int b  = idx >> 19;
    int d  = d8 << 3;
    const float4* cw4 = (const float4*)cw;
    float4 w[8];
    #pragma unroll
    for (int j = 0; j < 8; j++) w[j] = cw4[d + j];
    float acc[8];
    {
        float4 b0 = *(const float4*)&cb[d];
        float4 b1 = *(const float4*)&cb[d + 4];
        acc[0]=b0.x; acc[1]=b0.y; acc[2]=b0.z; acc[3]=b0.w;
        acc[4]=b1.x; acc[5]=b1.y; acc[6]=b1.z; acc[7]=b1.w;
    }
    #pragma unroll
    for (int k = 0; k < 4; k++) {
        int tt = t + k - 3;
        if (tt >= 0) {
            short8 v = *(const short8*)&xin16[((size_t)(b * L_SEQ + tt)) * DIN + d];
            #pragma unroll
            for (int j = 0; j < 8; j++)
                acc[j] = fmaf(h2f((u16)v[j]), (&w[j].x)[k], acc[j]);
        }
    }
    short8 o;
    #pragma unroll
    for (int j = 0; j < 8; j++) o[j] = (short)f2h_bits(siluf(acc[j]));
    *(short8*)&xc16[(size_t)idx * 8] = o;
}

// ---------------- GEMM2: [4096][2048] @ [48][2048]^T, K-split 8, tile M=64 ----------------
__global__ __launch_bounds__(256)
void gemm2_mfma(const u16* __restrict__ A, const u16* __restrict__ Bt, float* __restrict__ pb)
{
    __shared__ __align__(16) u16 As[64 * 64];
    __shared__ __align__(16) u16 Bs[48 * 64];
    const int tid = threadIdx.x, lane = tid & 63, w = tid >> 6;
    const int bm = blockIdx.x * 64;
    const int kz = blockIdx.y;
    const int arow = tid >> 2;          // 0..63
    const int au   = (tid & 3) << 1;    // unit pair
    f32x4 acc[3];
    acc[0] = acc[1] = acc[2] = (f32x4){0.f, 0.f, 0.f, 0.f};

    for (int it = 0; it < 4; ++it) {
        const int k0 = kz * 256 + it * 64;
        short8 ra0 = *(const short8*)&A[(size_t)(bm + arow) * DIN + k0 + au * 8];
        short8 ra1 = *(const short8*)&A[(size_t)(bm + arow) * DIN + k0 + (au + 1) * 8];
        short8 rb0, rb1;
        if (tid < 192) {
            rb0 = *(const short8*)&Bt[(size_t)arow * DIN + k0 + au * 8];
            rb1 = *(const short8*)&Bt[(size_t)arow * DIN + k0 + (au + 1) * 8];
        }
        __syncthreads();
        {
            int s0 = au ^ (arow & 7), s1 = (au + 1) ^ (arow & 7);
            *(short8*)&As[arow * 64 + s0 * 8] = ra0;
            *(short8*)&As[arow * 64 + s1 * 8] = ra1;
            if (tid < 192) {
                *(short8*)&Bs[arow * 64 + s0 * 8] = rb0;
                *(short8*)&Bs[arow * 64 + s1 * 8] = rb1;
            }
        }
        __syncthreads();
        #pragma unroll
        for (int kk = 0; kk < 2; kk++) {
            int r = w * 16 + (lane & 15);
            int sl = (kk * 4 + (lane >> 4)) ^ (r & 7);
            half8 af = *(const half8*)&As[r * 64 + sl * 8];
            #pragma unroll
            for (int ni = 0; ni < 3; ni++) {
                int br = ni * 16 + (lane & 15);
                int bsl = (kk * 4 + (lane >> 4)) ^ (br & 7);
                half8 bf = *(const half8*)&Bs[br * 64 + bsl * 8];
                acc[ni] = __builtin_amdgcn_mfma_f32_16x16x32_f16(af, bf, acc[ni], 0, 0, 0);
            }
        }
    }
    #pragma unroll
    for (int ni = 0; ni < 3; ni++) {
        #pragma unroll
        for (int q = 0; q < 4; q++) {
            int row = bm + w * 16 + (lane >> 4) * 4 + q;
            int col = ni * 16 + (lane & 15);
            pb[((size_t)kz * NROWS + row) * 48 + col] = acc[ni][q];
        }
    }
}

// ---------------- GEMM2 reduce: sum 8 partials, softplus col0, split B/C ----------------
__global__ __launch_bounds__(256)
void gemm2_reduce(const float* __restrict__ pb, float* __restrict__ delta,
                  float* __restrict__ Bm, float* __restrict__ Cm)
{
    int idx = blockIdx.x * 256 + threadIdx.x;      // 4096*48
    int row = idx / 48, col = idx - row * 48;
    float s = 0.f;
    #pragma unroll
    for (int kz = 0; kz < 8; kz++) s += pb[(size_t)kz * NROWS * 48 + idx];
    if (col == 0)       delta[row] = fmaxf(s, 0.f) + log1pf(__expf(-fabsf(s)));
    else if (col < 17)  Bm[row * NST + col - 1]  = s;
    else if (col < 33)  Cm[row * NST + col - 17] = s;
}

// ---------------- scan pass 1: thread-per-d, h[16] in regs ----------------
__global__ __launch_bounds__(256)
void scan_part1_reg(const u16* __restrict__ xc16, const float* __restrict__ delta,
                    const float* __restrict__ Bm, const float* __restrict__ A_log,
                    float* __restrict__ h_loc, float* __restrict__ Pc)
{
    const int b = blockIdx.z, c = blockIdx.y;
    const int d = blockIdx.x * 256 + threadIdx.x;
    float ka[16];
    {
        const float4* Av = (const float4*)(A_log + (size_t)d * 16);
        #pragma unroll
        for (int q = 0; q < 4; q++) {
            float4 a = Av[q];
            ka[q*4+0] = -__expf(a.x) * 1.44269504f;
            ka[q*4+1] = -__expf(a.y) * 1.44269504f;
            ka[q*4+2] = -__expf(a.z) * 1.44269504f;
            ka[q*4+3] = -__expf(a.w) * 1.44269504f;
        }
    }
    float h[16];
    #pragma unroll
    for (int n = 0; n < 16; n++) h[n] = 0.f;
    float S = 0.f;
    const int rowbase = b * L_SEQ + c * CL;
    #pragma unroll 2
    for (int t = 0; t < CL; ++t) {
        const int rowg = rowbase + t;
        const float dt = delta[rowg];
        const float4* Bv = (const float4*)(Bm + (size_t)rowg * 16);
        float4 b0 = Bv[0], b1 = Bv[1], b2 = Bv[2], b3 = Bv[3];
        float bb[16] = {b0.x,b0.y,b0.z,b0.w, b1.x,b1.y,b1.z,b1.w,
                        b2.x,b2.y,b2.z,b2.w, b3.x,b3.y,b3.z,b3.w};
        const float xt = h2f(xc16[(size_t)rowg * DIN + d]);
        const float dtx = dt * xt;
        S += dt;
        #pragma unroll
        for (int n = 0; n < 16; n++) {
            float a = fexp2(dt * ka[n]);
            h[n] = fmaf(a, h[n], bb[n] * dtx);
        }
    }
    float* hp = h_loc + (((size_t)(b * NC + c) * DIN) + d) * 16;
    float* pp = Pc    + (((size_t)(b * NC + c) * DIN) + d) * 16;
    #pragma unroll
    for (int q = 0; q < 4; q++) {
        *(float4*)&hp[q*4] = (float4){h[q*4+0], h[q*4+1], h[q*4+2], h[q*4+3]};
        *(float4*)&pp[q*4] = (float4){fexp2(S*ka[q*4+0]), fexp2(S*ka[q*4+1]),
                                      fexp2(S*ka[q*4+2]), fexp2(S*ka[q*4+3])};
    }
}

// ---------------- scan pass 2: sequential carry across chunks ----------------
__global__ __launch_bounds__(256)
void scan_carry(const float* __restrict__ h_loc, const float* __restrict__ Pc,
                float* __restrict__ H_in)
{
    int gid = blockIdx.x * 256 + threadIdx.x;      // NB*DIN*NST = 65536
    int b = gid >> 15, r = gid & 32767;
    float H = 0.f;
    for (int c = 0; c < NC; ++c) {
        size_t idx = ((size_t)(b * NC + c) << 15) + r;
        H_in[idx] = H;
        H = fmaf(Pc[idx], H, h_loc[idx]);
    }
}

// ---------------- scan pass 3: thread-per-d, fused epilogue -> y fp16 ----------------
__global__ __launch_bounds__(256)
void scan_part3_reg(const u16* __restrict__ xc16, const float* __restrict__ delta,
                    const float* __restrict__ Bm, const float* __restrict__ Cm,
                    const float* __restrict__ A_log, const float* __restrict__ Dp,
                    const u16* __restrict__ res16, const float* __restrict__ H_in,
                    u16* __restrict__ yh)
{
    const int b = blockIdx.z, c = blockIdx.y;
    const int d = blockIdx.x * 256 + threadIdx.x;
    float ka[16];
    {
        const float4* Av = (const float4*)(A_log + (size_t)d * 16);
        #pragma unroll
        for (int q = 0; q < 4; q++) {
            float4 a = Av[q];
            ka[q*4+0] = -__expf(a.x) * 1.44269504f;
            ka[q*4+1] = -__expf(a.y) * 1.44269504f;
            ka[q*4+2] = -__expf(a.z) * 1.44269504f;
            ka[q*4+3] = -__expf(a.w) * 1.44269504f;
        }
    }
    float h[16];
    {
        const float4* Hv = (const float4*)(H_in + (((size_t)(b * NC + c) * DIN) + d) * 16);
        #pragma unroll
        for (int q = 0; q < 4; q++) {
            float4 v = Hv[q];
            h[q*4+0]=v.x; h[q*4+1]=v.y; h[q*4+2]=v.z; h[q*4+3]=v.w;
        }
    }
    const float Dpd = Dp[d];
    const int rowbase = b * L_SEQ + c * CL;
    #pragma unroll 2
    for (int t = 0; t < CL; ++t) {
        const int rowg = rowbase + t;
        const float dt = delta[rowg];
        const float4* Bv = (const float4*)(Bm + (size_t)rowg * 16);
        const float4* Cv = (const float4*)(Cm + (size_t)rowg * 16);
        float4 b0 = Bv[0], b1 = Bv[1], b2 = Bv[2], b3 = Bv[3];
        float4 c0 = Cv[0], c1 = Cv[1], c2 = Cv[2], c3 = Cv[3];
        float bb[16] = {b0.x,b0.y,b0.z,b0.w, b1.x,b1.y,b1.z,b1.w,
                        b2.x,b2.y,b2.z,b2.w, b3.x,b3.y,b3.z,b3.w};
        float cc[16] = {c0.x,c0.y,c0.z,c0.w, c1.x,c1.y,c1.z,c1.w,
                        c2.x,c2.y,c2.z,c2.w, c3.x,c3.y,c3.z,c3.w};
        const float xt = h2f(xc16[(size_t)rowg * DIN + d]);
        const float rt = h2f(res16[(size_t)rowg * DIN + d]);
        const float dtx = dt * xt;
        float y = 0.f;
        #pragma unroll
        for (int n = 0; n < 16; n++) {
            float a = fexp2(dt * ka[n]);
            h[n] = fmaf(a, h[n], bb[n] * dtx);
            y = fmaf(cc[n], h[n], y);
        }
        y = (y + xt * Dpd) * rt;
        yh[(size_t)rowg * DIN + d] = f2h_bits(y);
    }
}

extern "C" void kernel_launch(void* const* d_in, const int* in_sizes, int n_in,
                              void* d_out, int out_size, void* d_ws, size_t ws_size,
                              hipStream_t stream)
{
    const float* x     = (const float*)d_in[0];
    const float* W_in  = (const float*)d_in[1];
    const float* cw    = (const float*)d_in[2];
    const float* cb    = (const float*)d_in[3];
    const float* Wx    = (const float*)d_in[4];
    const float* A_log = (const float*)d_in[5];
    const float* Dp    = (const float*)d_in[6];
    const float* W_out = (const float*)d_in[7];
    float* out = (float*)d_out;
    float* ws  = (float*)d_ws;

    // workspace (float slot offsets); aliases valid by stream-order lifetimes
    u16*   xin16 = (u16*)(ws);                     // [4096][2048] ; dead after conv
    u16*   y16   = (u16*)(ws);                     // alias
    u16*   res16 = (u16*)(ws + 4194304);           // [4096][2048]
    u16*   xc16  = (u16*)(ws + 8388608);           // [4096][2048]
    u16*   x16   = (u16*)(ws + 12582912);          // [4096][1024] ; dead after GEMM1
    u16*   p4    = (u16*)(ws + 12582912);          // [4][4096][1024] (alias x16+Bt1 region)
    u16*   Bt1   = (u16*)(ws + 14680064);          // [4096][1024] ; dead after GEMM1
    float* pb    = ws + 14680064;                  // [8][4096][48] f32 (alias Bt1; dead before GEMM3)
    u16*   WxT16 = (u16*)(ws + 20971520);          // [48][2048]
    float* delta = ws + 21020672;                  // 4096
    float* Bm    = ws + 21024768;                  // 65536
    float* Cm    = ws + 21090304;                  // 65536
    float* h_loc = ws + 21155840;                  // 2097152
    float* Pc    = ws + 23252992;                  // 2097152
    float* H_in  = ws + 25350144;                  // 2097152
    u16*   Bt3   = (u16*)(ws + 27447296);          // [1024][2048] (end 28495872 fl = 114 MB)

    dim3 blk(256), blk512(512);

    // 1) fused preprocessing
    prep_inputs<<<dim3(6016), blk, 0, stream>>>(x, W_in, W_out, Wx, x16, Bt1, Bt3, WxT16);
    // 2) GEMM1 (8-phase 256^2): xin16 | silu(res)16 ; grid 16x16 = 256 blocks
    gemm8<1><<<dim3(16, 16, 1), blk512, 0, stream>>>(x16, Bt1, xin16, res16,
                                                     NROWS, 2 * DIN, DMOD, DMOD, DMOD);
    // 3) conv + bias + silu
    conv_silu16<<<dim3(NB * L_SEQ * (DIN / 8) / 256), blk, 0, stream>>>(xin16, cw, cb, xc16);
    // 4) ssm params
    gemm2_mfma<<<dim3(NROWS / 64, 8), blk, 0, stream>>>(xc16, WxT16, pb);
    gemm2_reduce<<<dim3(NROWS * 48 / 256), blk, 0, stream>>>(pb, delta, Bm, Cm);
    // 5) chunk-parallel scan
    scan_part1_reg<<<dim3(DIN / 256, NC, NB), blk, 0, stream>>>(xc16, delta, Bm, A_log, h_loc, Pc);
    scan_carry<<<dim3(NB * DIN * NST / 256), blk, 0, stream>>>(h_loc, Pc, H_in);
    scan_part3_reg<<<dim3(DIN / 256, NC, NB), blk, 0, stream>>>(xc16, delta, Bm, Cm, A_log, Dp, res16, H_in, y16);
    // 6) GEMM3 (8-phase 256^2, split-K=4): grid (4,16,4) = 256 blocks, KLEN=512
    gemm8<2><<<dim3(DMOD / 256, NROWS / 256, 4), blk512, 0, stream>>>(y16, Bt3, p4, nullptr,
                                                                     NROWS, DMOD, DIN / 4, DIN, DIN);
    // 7) out = sum of 4 partials (fp32)
    add_partials4<<<dim3(NROWS * DMOD / 8 / 256), blk, 0, stream>>>(p4, out);
}

// Round 10
// 188.218 us; speedup vs baseline: 1.1482x; 1.1015x over previous
//
#include <hip/hip_runtime.h>

#define L_SEQ 2048
#define NB    2
#define DMOD  1024
#define DIN   2048
#define NST   16
#define NROWS (NB*L_SEQ)   // 4096
#define CL    64
#define NC    (L_SEQ/CL)   // 32

typedef unsigned short u16;
typedef _Float16 half8 __attribute__((ext_vector_type(8)));
typedef float f32x4 __attribute__((ext_vector_type(4)));
typedef short short8 __attribute__((ext_vector_type(8)));

__device__ __forceinline__ float siluf(float v){ return v / (1.f + __expf(-v)); }
__device__ __forceinline__ u16 f2h_bits(float v){ _Float16 h = (_Float16)v; return __builtin_bit_cast(u16, h); }
__device__ __forceinline__ float h2f(u16 v){ return (float)__builtin_bit_cast(_Float16, v); }
__device__ __forceinline__ float fexp2(float x){
#if __has_builtin(__builtin_amdgcn_exp2f)
    return __builtin_amdgcn_exp2f(x);
#else
    return __expf(x * 0.69314718056f);
#endif
}

// async global->LDS, 16B per lane; lds base wave-uniform; dest = base + lane*16
__device__ __forceinline__ void gload16(const u16* g, u16* l)
{
    __builtin_amdgcn_global_load_lds(
        (const __attribute__((address_space(1))) void*)g,
        (__attribute__((address_space(3))) void*)l,
        16, 0, 0);
}

#define BARRIER() do { asm volatile("" ::: "memory"); __builtin_amdgcn_s_barrier(); asm volatile("" ::: "memory"); } while (0)
#define VMCNT2()  asm volatile("s_waitcnt vmcnt(2)" ::: "memory")

// ---------------- fused input preprocessing ----------------
// blocks [0,4096): x f32 -> x16 ; [4096,5120): W_in^T f16 ; [5120,5632): W_out^T f16 ;
// [5632,6016): W_x -> WxT16 [48][2048] zero-padded
__global__ __launch_bounds__(256)
void prep_inputs(const float* __restrict__ x, const float* __restrict__ W_in,
                 const float* __restrict__ W_out, const float* __restrict__ Wx,
                 u16* __restrict__ x16, u16* __restrict__ Bt1,
                 u16* __restrict__ Bt3, u16* __restrict__ WxT16)
{
    __shared__ float s[64][65];
    const int bid = blockIdx.x, tid = threadIdx.x;
    if (bid < 4096) {
        int i = bid * 256 + tid;                   // over NROWS*DMOD/4
        float4 v = ((const float4*)x)[i];
        ushort4 o;
        o.x = f2h_bits(v.x); o.y = f2h_bits(v.y); o.z = f2h_bits(v.z); o.w = f2h_bits(v.w);
        *(ushort4*)&x16[(size_t)i * 4] = o;
    } else if (bid < 5632) {
        const float* in; u16* outT; int R, C, rblk, cblk;
        if (bid < 5120) { int b = bid - 4096; in = W_in;  outT = Bt1; R = 1024; C = 4096; cblk = b & 63; rblk = b >> 6; }
        else            { int b = bid - 5120; in = W_out; outT = Bt3; R = 2048; C = 1024; cblk = b & 15; rblk = b >> 4; }
        int r0 = rblk * 64, c0 = cblk * 64;
        int tc = tid & 63, ty = tid >> 6;
        #pragma unroll
        for (int j = 0; j < 16; j++) {
            int r = ty + j * 4;
            s[r][tc] = in[(size_t)(r0 + r) * C + c0 + tc];
        }
        __syncthreads();
        #pragma unroll
        for (int j = 0; j < 16; j++) {
            int nn = ty + j * 4;
            outT[(size_t)(c0 + nn) * R + r0 + tc] = f2h_bits(s[tc][nn]);
        }
    } else {
        int idx = (bid - 5632) * 256 + tid;        // 48*2048
        int n = idx >> 11, k = idx & 2047;
        float v = (n < 33) ? Wx[k * 33 + n] : 0.f;
        WxT16[idx] = f2h_bits(v);
    }
}

// ---------------- 4-phase MFMA GEMM: 256x256 tile, BK=64, 8 waves, 512 thr --------------
// Raw s_barrier + counted vmcnt(2); never drains to 0 in the loop. NO setprio (lockstep
// schedule: prio-1 MFMA waves starve prio-0 read waves -> kills cross-wave overlap).
// Stage order per tile t+1: ph0 A-h0, ph1 A-h1, ph2 B-h0, ph3 B-h1 (into buf (t+1)&1).
// Compute partition: ph0 (kk0, ni01), ph1 (kk0, ni23), ph2 (kk1, ni01), ph3 (kk1, ni23).
// EPI==1: split N at half: col<half -> C0h (u16) ; else C1h = silu (u16)
// EPI==2: u16 partial at C0h[(z*M + row)*N + col]
template<int EPI>
__global__ __launch_bounds__(512, 2)
void gemm8(const u16* __restrict__ A, const u16* __restrict__ Bt,
           void* __restrict__ C0v, void* __restrict__ C1v,
           int M, int N, int KLEN, int lda, int ldb)
{
    __shared__ __align__(16) u16 As[2 * 256 * 64];   // 64 KB (2 bufs)
    __shared__ __align__(16) u16 Bs[2 * 256 * 64];   // 64 KB
    const int tid  = threadIdx.x;
    const int lane = tid & 63;
    const int w    = tid >> 6;                 // 0..7
    const int wm   = w >> 2, wn = w & 3;       // 2 x 4 wave grid
    const int bm = blockIdx.y * 256, bn = blockIdx.x * 256;
    const int kBase = blockIdx.z * KLEN;

    // staging: lane l -> row +(l>>3), 16B unit (l&7); source pre-swizzled unit
    const int srow8 = lane >> 3;
    const int sunit = (lane & 7) ^ srow8;
    const u16* Ag = A  + (size_t)(bm + srow8) * lda + kBase + sunit * 8;
    const u16* Bg = Bt + (size_t)(bn + srow8) * ldb + kBase + sunit * 8;
    const int rw = w * 16;                     // wave's stage-row base within a half

    // fragment offsets (elements within one buf); kk=1 -> ^32
    const int fr  = lane & 15;
    const int sl0 = ((lane >> 4) ^ (fr & 7)) * 8;
    int aOffs[8], bOffs[4];
    #pragma unroll
    for (int mi = 0; mi < 8; mi++) aOffs[mi] = (wm * 128 + mi * 16 + fr) * 64 + sl0;
    #pragma unroll
    for (int ni = 0; ni < 4; ni++) bOffs[ni] = (ni * 64 + wn * 16 + fr) * 64 + sl0;

    f32x4 acc[8][4];
    #pragma unroll
    for (int i = 0; i < 8; i++)
        #pragma unroll
        for (int j = 0; j < 4; j++)
            acc[i][j] = (f32x4){0.f, 0.f, 0.f, 0.f};

    // stage one half-tile (2 gloads): rows h*128+rw..+15 of next-buf operand
    auto stage2 = [&](const u16* G, int ld, int rbase, int kcol, u16* ldsDst) {
        gload16(G + (size_t)rbase * ld + kcol, ldsDst);
        gload16(G + (size_t)(rbase + 8) * ld + kcol, ldsDst + 8 * 64);
    };

    const int NT = KLEN >> 6;
    // prologue: stage tile 0 fully into buf 0
    stage2(Ag, lda, 0 + rw, 0, &As[(0 + rw) * 64]);
    stage2(Ag, lda, 128 + rw, 0, &As[(128 + rw) * 64]);
    stage2(Bg, ldb, 0 + rw, 0, &Bs[(0 + rw) * 64]);
    stage2(Bg, ldb, 128 + rw, 0, &Bs[(128 + rw) * 64]);
    VMCNT2();
    BARRIER();

    for (int t = 0; t < NT; ++t) {
        const int cO = (t & 1) << 14;          // current buf elem offset
        const int nO = cO ^ 16384;             // next buf
        const int kn = (t + 1) << 6;
        const bool pf = (t + 1) < NT;
        half8 af[8], bf0, bf1;

        // ---- phase 0: A kk0 (8 reads) + B kk0 ni{0,1}; stage A-h0(t+1)
        #pragma unroll
        for (int mi = 0; mi < 8; mi++) af[mi] = *(const half8*)&As[cO + aOffs[mi]];
        bf0 = *(const half8*)&Bs[cO + bOffs[0]];
        bf1 = *(const half8*)&Bs[cO + bOffs[1]];
        if (pf) stage2(Ag, lda, 0 + rw, kn, &As[nO + (0 + rw) * 64]);
        BARRIER();
        #pragma unroll
        for (int mi = 0; mi < 8; mi++) acc[mi][0] = __builtin_amdgcn_mfma_f32_16x16x32_f16(af[mi], bf0, acc[mi][0], 0, 0, 0);
        #pragma unroll
        for (int mi = 0; mi < 8; mi++) acc[mi][1] = __builtin_amdgcn_mfma_f32_16x16x32_f16(af[mi], bf1, acc[mi][1], 0, 0, 0);
        VMCNT2();
        BARRIER();

        // ---- phase 1: B kk0 ni{2,3}; stage A-h1(t+1)
        bf0 = *(const half8*)&Bs[cO + bOffs[2]];
        bf1 = *(const half8*)&Bs[cO + bOffs[3]];
        if (pf) stage2(Ag, lda, 128 + rw, kn, &As[nO + (128 + rw) * 64]);
        BARRIER();
        #pragma unroll
        for (int mi = 0; mi < 8; mi++) acc[mi][2] = __builtin_amdgcn_mfma_f32_16x16x32_f16(af[mi], bf0, acc[mi][2], 0, 0, 0);
        #pragma unroll
        for (int mi = 0; mi < 8; mi++) acc[mi][3] = __builtin_amdgcn_mfma_f32_16x16x32_f16(af[mi], bf1, acc[mi][3], 0, 0, 0);
        BARRIER();

        // ---- phase 2: A kk1 (8 reads) + B kk1 ni{0,1}; stage B-h0(t+1)
        #pragma unroll
        for (int mi = 0; mi < 8; mi++) af[mi] = *(const half8*)&As[cO + (aOffs[mi] ^ 32)];
        bf0 = *(const half8*)&Bs[cO + (bOffs[0] ^ 32)];
        bf1 = *(const half8*)&Bs[cO + (bOffs[1] ^ 32)];
        if (pf) stage2(Bg, ldb, 0 + rw, kn, &Bs[nO + (0 + rw) * 64]);
        BARRIER();
        #pragma unroll
        for (int mi = 0; mi < 8; mi++) acc[mi][0] = __builtin_amdgcn_mfma_f32_16x16x32_f16(af[mi], bf0, acc[mi][0], 0, 0, 0);
        #pragma unroll
        for (int mi = 0; mi < 8; mi++) acc[mi][1] = __builtin_amdgcn_mfma_f32_16x16x32_f16(af[mi], bf1, acc[mi][1], 0, 0, 0);
        BARRIER();

        // ---- phase 3: B kk1 ni{2,3}; stage B-h1(t+1)
        bf0 = *(const half8*)&Bs[cO + (bOffs[2] ^ 32)];
        bf1 = *(const half8*)&Bs[cO + (bOffs[3] ^ 32)];
        if (pf) stage2(Bg, ldb, 128 + rw, kn, &Bs[nO + (128 + rw) * 64]);
        BARRIER();
        #pragma unroll
        for (int mi = 0; mi < 8; mi++) acc[mi][2] = __builtin_amdgcn_mfma_f32_16x16x32_f16(af[mi], bf0, acc[mi][2], 0, 0, 0);
        #pragma unroll
        for (int mi = 0; mi < 8; mi++) acc[mi][3] = __builtin_amdgcn_mfma_f32_16x16x32_f16(af[mi], bf1, acc[mi][3], 0, 0, 0);
        VMCNT2();
        BARRIER();
    }

    const int cr = (lane >> 4) * 4;
    #pragma unroll
    for (int mi = 0; mi < 8; mi++) {
        #pragma unroll
        for (int ni = 0; ni < 4; ni++) {
            #pragma unroll
            for (int q = 0; q < 4; q++) {
                int row = bm + wm * 128 + mi * 16 + cr + q;
                int col = bn + ni * 64 + wn * 16 + fr;
                float v = acc[mi][ni][q];
                if (EPI == 1) {
                    int half = N >> 1;
                    if (col < half) ((u16*)C0v)[(size_t)row * half + col] = f2h_bits(v);
                    else            ((u16*)C1v)[(size_t)row * half + col - half] = f2h_bits(siluf(v));
                } else {
                    ((u16*)C0v)[((size_t)blockIdx.z * M + row) * N + col] = f2h_bits(v);
                }
            }
        }
    }
}

// ---------------- sum the four split-K f16 partials -> fp32 out ----------------
__global__ __launch_bounds__(256)
void add_partials4(const u16* __restrict__ p, float* __restrict__ out)
{
    int i = blockIdx.x * 256 + threadIdx.x;        // over 4096*1024/8
    const size_t stride = (size_t)NROWS * DMOD;
    float acc[8] = {0,0,0,0,0,0,0,0};
    #pragma unroll
    for (int z = 0; z < 4; z++) {
        short8 a = *(const short8*)&p[z * stride + (size_t)i * 8];
        #pragma unroll
        for (int j = 0; j < 8; j++) acc[j] += h2f((u16)a[j]);
    }
    float4 o0 = {acc[0], acc[1], acc[2], acc[3]};
    float4 o1 = {acc[4], acc[5], acc[6], acc[7]};
    *(float4*)&out[(size_t)i * 8]     = o0;
    *(float4*)&out[(size_t)i * 8 + 4] = o1;
}

// ---------------- depthwise causal conv + bias + SiLU, LDS-tiled (32t x 128d / block) ----
__global__ __launch_bounds__(256)
void conv_silu16t(const u16* __restrict__ xin16, const float* __restrict__ cw,
                  const float* __restrict__ cb, u16* __restrict__ xc16)
{
    __shared__ u16 sx[35][136];                    // padded stride: conflict-free reads
    const int d0 = blockIdx.x << 7, t0 = blockIdx.y << 5, b = blockIdx.z;
    const int tid = threadIdx.x;
    // stage rows t0-3 .. t0+31 (35 rows x 128 ch), zero-fill t<0
    for (int i = tid; i < 35 * 16; i += 256) {
        int r = i >> 4, u = i & 15;
        int t = t0 - 3 + r;
        short8 v = {0,0,0,0,0,0,0,0};
        if (t >= 0) v = *(const short8*)&xin16[((size_t)(b * L_SEQ + t)) * DIN + d0 + u * 8];
        *(short8*)&sx[r][u * 8] = v;
    }
    __syncthreads();
    const int u  = tid & 15;                       // d-unit (8 channels)
    const int tl = tid >> 4;                       // 0..15
    const int d  = d0 + u * 8;
    const float4* cw4 = (const float4*)cw;
    float4 w[8];
    #pragma unroll
    for (int j = 0; j < 8; j++) w[j] = cw4[d + j];
    float bias[8];
    {
        float4 b0 = *(const float4*)&cb[d];
        float4 b1 = *(const float4*)&cb[d + 4];
        bias[0]=b0.x; bias[1]=b0.y; bias[2]=b0.z; bias[3]=b0.w;
        bias[4]=b1.x; bias[5]=b1.y; bias[6]=b1.z; bias[7]=b1.w;
    }
    #pragma unroll
    for (int half = 0; half < 2; half++) {
        const int t_l = tl + half * 16;            // local output t
        float acc[8];
        #pragma unroll
        for (int j = 0; j < 8; j++) acc[j] = bias[j];
        #pragma unroll
        for (int k = 0; k < 4; k++) {
            short8 v = *(const short8*)&sx[t_l + k][u * 8];
            #pragma unroll
            for (int j = 0; j < 8; j++)
                acc[j] = fmaf(h2f((u16)v[j]), (&w[j].x)[k], acc[j]);
        }
        short8 o;
        #pragma unroll
        for (int j = 0; j < 8; j++) o[j] = (short)f2h_bits(siluf(acc[j]));
        *(short8*)&xc16[((size_t)(b * L_SEQ + t0 + t_l)) * DIN + d] = o;
    }
}

// ---------------- GEMM2: [4096][2048] @ [48][2048]^T, K-split 8, tile M=64 ----------------
__global__ __launch_bounds__(256)
void gemm2_mfma(const u16* __restrict__ A, const u16* __restrict__ Bt, float* __restrict__ pb)
{
    __shared__ __align__(16) u16 As[64 * 64];
    __shared__ __align__(16) u16 Bs[48 * 64];
    const int tid = threadIdx.x, lane = tid & 63, w = tid >> 6;
    const int bm = blockIdx.x * 64;
    const int kz = blockIdx.y;
    const int arow = tid >> 2;          // 0..63
    const int au   = (tid & 3) << 1;    // unit pair
    f32x4 acc[3];
    acc[0] = acc[1] = acc[2] = (f32x4){0.f, 0.f, 0.f, 0.f};

    for (int it = 0; it < 4; ++it) {
        const int k0 = kz * 256 + it * 64;
        short8 ra0 = *(const short8*)&A[(size_t)(bm + arow) * DIN + k0 + au * 8];
        short8 ra1 = *(const short8*)&A[(size_t)(bm + arow) * DIN + k0 + (au + 1) * 8];
        short8 rb0, rb1;
        if (tid < 192) {
            rb0 = *(const short8*)&Bt[(size_t)arow * DIN + k0 + au * 8];
            rb1 = *(const short8*)&Bt[(size_t)arow * DIN + k0 + (au + 1) * 8];
        }
        __syncthreads();
        {
            int s0 = au ^ (arow & 7), s1 = (au + 1) ^ (arow & 7);
            *(short8*)&As[arow * 64 + s0 * 8] = ra0;
            *(short8*)&As[arow * 64 + s1 * 8] = ra1;
            if (tid < 192) {
                *(short8*)&Bs[arow * 64 + s0 * 8] = rb0;
                *(short8*)&Bs[arow * 64 + s1 * 8] = rb1;
            }
        }
        __syncthreads();
        #pragma unroll
        for (int kk = 0; kk < 2; kk++) {
            int r = w * 16 + (lane & 15);
            int sl = (kk * 4 + (lane >> 4)) ^ (r & 7);
            half8 af = *(const half8*)&As[r * 64 + sl * 8];
            #pragma unroll
            for (int ni = 0; ni < 3; ni++) {
                int br = ni * 16 + (lane & 15);
                int bsl = (kk * 4 + (lane >> 4)) ^ (br & 7);
                half8 bf = *(const half8*)&Bs[br * 64 + bsl * 8];
                acc[ni] = __builtin_amdgcn_mfma_f32_16x16x32_f16(af, bf, acc[ni], 0, 0, 0);
            }
        }
    }
    #pragma unroll
    for (int ni = 0; ni < 3; ni++) {
        #pragma unroll
        for (int q = 0; q < 4; q++) {
            int row = bm + w * 16 + (lane >> 4) * 4 + q;
            int col = ni * 16 + (lane & 15);
            pb[((size_t)kz * NROWS + row) * 48 + col] = acc[ni][q];
        }
    }
}

// ---------------- GEMM2 reduce: sum 8 partials, softplus col0, split B/C ----------------
__global__ __launch_bounds__(256)
void gemm2_reduce(const float* __restrict__ pb, float* __restrict__ delta,
                  float* __restrict__ Bm, float* __restrict__ Cm)
{
    int idx = blockIdx.x * 256 + threadIdx.x;      // 4096*48
    int row = idx / 48, col = idx - row * 48;
    float s = 0.f;
    #pragma unroll
    for (int kz = 0; kz < 8; kz++) s += pb[(size_t)kz * NROWS * 48 + idx];
    if (col == 0)       delta[row] = fmaxf(s, 0.f) + log1pf(__expf(-fabsf(s)));
    else if (col < 17)  Bm[row * NST + col - 1]  = s;
    else if (col < 33)  Cm[row * NST + col - 17] = s;
}

// ---------------- scan pass 1: thread-per-d, h[16] in regs ----------------
__global__ __launch_bounds__(256)
void scan_part1_reg(const u16* __restrict__ xc16, const float* __restrict__ delta,
                    const float* __restrict__ Bm, const float* __restrict__ A_log,
                    float* __restrict__ h_loc, float* __restrict__ Pc)
{
    const int b = blockIdx.z, c = blockIdx.y;
    const int d = blockIdx.x * 256 + threadIdx.x;
    float ka[16];
    {
        const float4* Av = (const float4*)(A_log + (size_t)d * 16);
        #pragma unroll
        for (int q = 0; q < 4; q++) {
            float4 a = Av[q];
            ka[q*4+0] = -__expf(a.x) * 1.44269504f;
            ka[q*4+1] = -__expf(a.y) * 1.44269504f;
            ka[q*4+2] = -__expf(a.z) * 1.44269504f;
            ka[q*4+3] = -__expf(a.w) * 1.44269504f;
        }
    }
    float h[16];
    #pragma unroll
    for (int n = 0; n < 16; n++) h[n] = 0.f;
    float S = 0.f;
    const int rowbase = b * L_SEQ + c * CL;
    #pragma unroll 2
    for (int t = 0; t < CL; ++t) {
        const int rowg = rowbase + t;
        const float dt = delta[rowg];
        const float4* Bv = (const float4*)(Bm + (size_t)rowg * 16);
        float4 b0 = Bv[0], b1 = Bv[1], b2 = Bv[2], b3 = Bv[3];
        float bb[16] = {b0.x,b0.y,b0.z,b0.w, b1.x,b1.y,b1.z,b1.w,
                        b2.x,b2.y,b2.z,b2.w, b3.x,b3.y,b3.z,b3.w};
        const float xt = h2f(xc16[(size_t)rowg * DIN + d]);
        const float dtx = dt * xt;
        S += dt;
        #pragma unroll
        for (int n = 0; n < 16; n++) {
            float a = fexp2(dt * ka[n]);
            h[n] = fmaf(a, h[n], bb[n] * dtx);
        }
    }
    float* hp = h_loc + (((size_t)(b * NC + c) * DIN) + d) * 16;
    float* pp = Pc    + (((size_t)(b * NC + c) * DIN) + d) * 16;
    #pragma unroll
    for (int q = 0; q < 4; q++) {
        *(float4*)&hp[q*4] = (float4){h[q*4+0], h[q*4+1], h[q*4+2], h[q*4+3]};
        *(float4*)&pp[q*4] = (float4){fexp2(S*ka[q*4+0]), fexp2(S*ka[q*4+1]),
                                      fexp2(S*ka[q*4+2]), fexp2(S*ka[q*4+3])};
    }
}

// ---------------- scan pass 2: sequential carry across chunks ----------------
__global__ __launch_bounds__(256)
void scan_carry(const float* __restrict__ h_loc, const float* __restrict__ Pc,
                float* __restrict__ H_in)
{
    int gid = blockIdx.x * 256 + threadIdx.x;      // NB*DIN*NST = 65536
    int b = gid >> 15, r = gid & 32767;
    float H = 0.f;
    for (int c = 0; c < NC; ++c) {
        size_t idx = ((size_t)(b * NC + c) << 15) + r;
        H_in[idx] = H;
        H = fmaf(Pc[idx], H, h_loc[idx]);
    }
}

// ---------------- scan pass 3: thread-per-d, fused epilogue -> y fp16 ----------------
__global__ __launch_bounds__(256)
void scan_part3_reg(const u16* __restrict__ xc16, const float* __restrict__ delta,
                    const float* __restrict__ Bm, const float* __restrict__ Cm,
                    const float* __restrict__ A_log, const float* __restrict__ Dp,
                    const u16* __restrict__ res16, const float* __restrict__ H_in,
                    u16* __restrict__ yh)
{
    const int b = blockIdx.z, c = blockIdx.y;
    const int d = blockIdx.x * 256 + threadIdx.x;
    float ka[16];
    {
        const float4* Av = (const float4*)(A_log + (size_t)d * 16);
        #pragma unroll
        for (int q = 0; q < 4; q++) {
            float4 a = Av[q];
            ka[q*4+0] = -__expf(a.x) * 1.44269504f;
            ka[q*4+1] = -__expf(a.y) * 1.44269504f;
            ka[q*4+2] = -__expf(a.z) * 1.44269504f;
            ka[q*4+3] = -__expf(a.w) * 1.44269504f;
        }
    }
    float h[16];
    {
        const float4* Hv = (const float4*)(H_in + (((size_t)(b * NC + c) * DIN) + d) * 16);
        #pragma unroll
        for (int q = 0; q < 4; q++) {
            float4 v = Hv[q];
            h[q*4+0]=v.x; h[q*4+1]=v.y; h[q*4+2]=v.z; h[q*4+3]=v.w;
        }
    }
    const float Dpd = Dp[d];
    const int rowbase = b * L_SEQ + c * CL;
    #pragma unroll 2
    for (int t = 0; t < CL; ++t) {
        const int rowg = rowbase + t;
        const float dt = delta[rowg];
        const float4* Bv = (const float4*)(Bm + (size_t)rowg * 16);
        const float4* Cv = (const float4*)(Cm + (size_t)rowg * 16);
        float4 b0 = Bv[0], b1 = Bv[1], b2 = Bv[2], b3 = Bv[3];
        float4 c0 = Cv[0], c1 = Cv[1], c2 = Cv[2], c3 = Cv[3];
        float bb[16] = {b0.x,b0.y,b0.z,b0.w, b1.x,b1.y,b1.z,b1.w,
                        b2.x,b2.y,b2.z,b2.w, b3.x,b3.y,b3.z,b3.w};
        float cc[16] = {c0.x,c0.y,c0.z,c0.w, c1.x,c1.y,c1.z,c1.w,
                        c2.x,c2.y,c2.z,c2.w, c3.x,c3.y,c3.z,c3.w};
        const float xt = h2f(xc16[(size_t)rowg * DIN + d]);
        const float rt = h2f(res16[(size_t)rowg * DIN + d]);
        const float dtx = dt * xt;
        float y = 0.f;
        #pragma unroll
        for (int n = 0; n < 16; n++) {
            float a = fexp2(dt * ka[n]);
            h[n] = fmaf(a, h[n], bb[n] * dtx);
            y = fmaf(cc[n], h[n], y);
        }
        y = (y + xt * Dpd) * rt;
        yh[(size_t)rowg * DIN + d] = f2h_bits(y);
    }
}

extern "C" void kernel_launch(void* const* d_in, const int* in_sizes, int n_in,
                              void* d_out, int out_size, void* d_ws, size_t ws_size,
                              hipStream_t stream)
{
    const float* x     = (const float*)d_in[0];
    const float* W_in  = (const float*)d_in[1];
    const float* cw    = (const float*)d_in[2];
    const float* cb    = (const float*)d_in[3];
    const float* Wx    = (const float*)d_in[4];
    const float* A_log = (const float*)d_in[5];
    const float* Dp    = (const float*)d_in[6];
    const float* W_out = (const float*)d_in[7];
    float* out = (float*)d_out;
    float* ws  = (float*)d_ws;

    // workspace (float slot offsets); aliases valid by stream-order lifetimes
    u16*   xin16 = (u16*)(ws);                     // [4096][2048] ; dead after conv
    u16*   y16   = (u16*)(ws);                     // alias
    u16*   res16 = (u16*)(ws + 4194304);           // [4096][2048]
    u16*   xc16  = (u16*)(ws + 8388608);           // [4096][2048]
    u16*   x16   = (u16*)(ws + 12582912);          // [4096][1024] ; dead after GEMM1
    u16*   p4    = (u16*)(ws + 12582912);          // [4][4096][1024] (alias x16+Bt1 region)
    u16*   Bt1   = (u16*)(ws + 14680064);          // [4096][1024] ; dead after GEMM1
    float* pb    = ws + 14680064;                  // [8][4096][48] f32 (alias Bt1; dead before GEMM3)
    u16*   WxT16 = (u16*)(ws + 20971520);          // [48][2048]
    float* delta = ws + 21020672;                  // 4096
    float* Bm    = ws + 21024768;                  // 65536
    float* Cm    = ws + 21090304;                  // 65536
    float* h_loc = ws + 21155840;                  // 2097152
    float* Pc    = ws + 23252992;                  // 2097152
    float* H_in  = ws + 25350144;                  // 2097152
    u16*   Bt3   = (u16*)(ws + 27447296);          // [1024][2048] (end 28495872 fl = 114 MB)

    dim3 blk(256), blk512(512);

    // 1) fused preprocessing
    prep_inputs<<<dim3(6016), blk, 0, stream>>>(x, W_in, W_out, Wx, x16, Bt1, Bt3, WxT16);
    // 2) GEMM1 (4-phase 256^2): xin16 | silu(res)16 ; grid 16x16 = 256 blocks
    gemm8<1><<<dim3(16, 16, 1), blk512, 0, stream>>>(x16, Bt1, xin16, res16,
                                                     NROWS, 2 * DIN, DMOD, DMOD, DMOD);
    // 3) conv + bias + silu (LDS-tiled)
    conv_silu16t<<<dim3(DIN / 128, L_SEQ / 32, NB), blk, 0, stream>>>(xin16, cw, cb, xc16);
    // 4) ssm params
    gemm2_mfma<<<dim3(NROWS / 64, 8), blk, 0, stream>>>(xc16, WxT16, pb);
    gemm2_reduce<<<dim3(NROWS * 48 / 256), blk, 0, stream>>>(pb, delta, Bm, Cm);
    // 5) chunk-parallel scan
    scan_part1_reg<<<dim3(DIN / 256, NC, NB), blk, 0, stream>>>(xc16, delta, Bm, A_log, h_loc, Pc);
    scan_carry<<<dim3(NB * DIN * NST / 256), blk, 0, stream>>>(h_loc, Pc, H_in);
    scan_part3_reg<<<dim3(DIN / 256, NC, NB), blk, 0, stream>>>(xc16, delta, Bm, Cm, A_log, Dp, res16, H_in, y16);
    // 6) GEMM3 (4-phase 256^2, split-K=4): grid (4,16,4) = 256 blocks, KLEN=512
    gemm8<2><<<dim3(DMOD / 256, NROWS / 256, 4), blk512, 0, stream>>>(y16, Bt3, p4, nullptr,
                                                                     NROWS, DMOD, DIN / 4, DIN, DIN);
    // 7) out = sum of 4 partials (fp32)
    add_partials4<<<dim3(NROWS * DMOD / 8 / 256), blk, 0, stream>>>(p4, out);
}